// Round 8
// baseline (35.192 us; speedup 1.0000x reference)
//
#include <hip/hip_runtime.h>
#include <cstdint>

#define IN_F 4096
#define OUT_F 11008
#define Q_OUT 5504
#define GROUP 128
#define BATCH 32

#define KBS 16           // k-splits (gridDim.y)
#define GPB 2            // quant groups per block
#define NCH 4            // 64-k chunks per block (K=256)
#define BN 128           // output cols per block (64 packed ints)
#define BST 21           // b_lds dword stride per nw-row: 16 data + 5 pad
                         // writes 2-way, frag reads 2-way (both free, m136)

typedef int   i32x4 __attribute__((ext_vector_type(4)));
typedef float f32x4 __attribute__((ext_vector_type(4)));

// ---------------------------------------------------------------------------
// Prep kernel, two roles by blockIdx:
//  blocks 0..31: row m: maxabs -> delta[m]; quantize x to i8 in MFMA A-frag
//    order; per-group row sums Sx[g][m] (i32, exact).
//  blocks 32..117: out[m][n] = bias[n]  (16 floats/thread; gemm atomics add)
// ---------------------------------------------------------------------------
__global__ __launch_bounds__(256)
void prep_kernel(const float* __restrict__ x,
                 const float* __restrict__ bias,
                 uint4* __restrict__ xq,     // 8192 slots of 16 i8
                 int*   __restrict__ Sx,     // [32 g][32 m]
                 float* __restrict__ delta,  // [32]
                 float* __restrict__ out)
{
    const int t = threadIdx.x;
    if (blockIdx.x >= 32) {
        const int base = (blockIdx.x - 32) * 4096 + t * 16;
        #pragma unroll
        for (int i = 0; i < 4; ++i)
            *reinterpret_cast<float4*>(out + base + i * 4) =
                *reinterpret_cast<const float4*>(bias + ((base + i * 4) % OUT_F));
        return;
    }
    const int m = blockIdx.x;
    const float* xr = x + (size_t)m * IN_F + t * 16;  // thread owns k=16t..16t+15
    float4 v[4];
    #pragma unroll
    for (int i = 0; i < 4; ++i) v[i] = reinterpret_cast<const float4*>(xr)[i];

    float lm = 0.f;
    #pragma unroll
    for (int i = 0; i < 4; ++i) {
        lm = fmaxf(lm, fmaxf(fmaxf(fabsf(v[i].x), fabsf(v[i].y)),
                             fmaxf(fabsf(v[i].z), fabsf(v[i].w))));
    }
    #pragma unroll
    for (int d = 32; d; d >>= 1) lm = fmaxf(lm, __shfl_xor(lm, d));
    __shared__ float wred[4];
    if ((t & 63) == 0) wred[t >> 6] = lm;
    __syncthreads();
    const float mx  = fmaxf(fmaxf(wred[0], wred[1]), fmaxf(wred[2], wred[3]));
    const float inv = mx > 0.f ? 127.0f / mx : 0.f;

    int q[16];
    #pragma unroll
    for (int i = 0; i < 4; ++i) {
        q[i * 4 + 0] = __float2int_rn(v[i].x * inv);
        q[i * 4 + 1] = __float2int_rn(v[i].y * inv);
        q[i * 4 + 2] = __float2int_rn(v[i].z * inv);
        q[i * 4 + 3] = __float2int_rn(v[i].w * inv);
    }
    uint4 w;
    uint* wp = reinterpret_cast<uint*>(&w);
    #pragma unroll
    for (int i = 0; i < 4; ++i)
        wp[i] = (q[i*4] & 255) | ((q[i*4+1] & 255) << 8) |
                ((q[i*4+2] & 255) << 16) | ((q[i*4+3] & 255) << 24);
    // slot = S*128 + f*64 + kg*16 + (m&15);  S=t>>2, kg=t&3, f=m>>4
    xq[(t >> 2) * 128 + (m >> 4) * 64 + (t & 3) * 16 + (m & 15)] = w;

    int psum = 0;
    #pragma unroll
    for (int i = 0; i < 16; ++i) psum += q[i];
    #pragma unroll
    for (int d = 4; d; d >>= 1) psum += __shfl_down(psum, d, 8);
    if ((t & 7) == 0) Sx[(t >> 3) * 32 + m] = psum;   // g = t>>3
    if (t == 0) delta[m] = mx * (1.0f / 127.0f);
}

// ---------------------------------------------------------------------------
// GEMM: per block M=32, N=128, K=256 (2 groups). 4 waves, each 32 cols.
// B loads: thread owns a 4-row x 4-int tile -> 4 x dwordx4; per instruction
//   16 lanes cover 256 CONTIGUOUS bytes of one qw row (2x the run length of
//   prior rounds, half the instructions). In-register 4x4 byte transpose
//   (qw ints are 0..255 so upper bytes are zero) -> 4 x b32 LDS writes.
// A: i8 frags direct from global xq (L2-hot), prefetched AFTER consumption.
// LDS: b_lds[2][64*21] dwords (10.75 KB); writes and reads both <=2-way.
// Per group (2 chunks): acc_i32 -> accf += s*(D - z*Sx).
// Epilogue: out += delta_m * accf via unsafeAtomicAdd (out = bias by prep).
// ---------------------------------------------------------------------------
__global__ __launch_bounds__(256, 3)
void int4_gemm_i8(const uint4* __restrict__ xq,
                  const int*   __restrict__ qw,
                  const float* __restrict__ scales,
                  const int*   __restrict__ qz,
                  const int*   __restrict__ Sx,
                  const float* __restrict__ delta,
                  float*       __restrict__ out)
{
    const int tid  = threadIdx.x;
    const int lane = tid & 63;
    const int wid  = tid >> 6;            // 0..3
    const int nb   = blockIdx.x;          // 0..85
    const int kb   = blockIdx.y;          // 0..15
    const int g0   = kb * GPB;
    const int k0b  = kb * (NCH * 64);     // block k base (256)

    __shared__ int b_lds[2][64 * BST];    // 2 x 5.25 KB

    const int cl  = lane & 15;
    const int kg  = lane >> 4;
    const int n   = nb * BN + wid * 32 + (0) * 16 + cl;  // nf added per-frag
    const int shn = (cl & 1) * 4;

    // per-group dequant constants for both n-frags
    float sv[GPB][2];
    int   zv[GPB][2];
    #pragma unroll
    for (int g = 0; g < GPB; ++g)
        #pragma unroll
        for (int nf = 0; nf < 2; ++nf) {
            const int nn = n + nf * 16;
            sv[g][nf] = scales[(size_t)(g0 + g) * OUT_F + nn];
            zv[g][nf] = (qz[(size_t)(g0 + g) * Q_OUT + (nn >> 1)] >> shn) & 15;
        }

    // B staging geometry: c16 = int-quad column, qr = row-quad within wave
    const int c16 = lane & 15;            // ints 4*c16 .. 4*c16+3
    const int qr  = lane >> 4;            // rows 16*wid + 4*qr + r

    uint4 d[2][4];                        // [set][row] 4-row x 4-int tiles
    uint4 A[2][2];                        // [set][f] A fragments (16 i8)
    i32x4 acc_i[2][2] = {};               // [f][nf]
    f32x4 accf[2][2]  = {};
    int4  sx0v = {}, sx1v = {};

    auto LOADB = [&](int c, int set) {
        const int kr = k0b + c * 64 + 16 * wid + 4 * qr;
        #pragma unroll
        for (int r = 0; r < 4; ++r)
            d[set][r] = *reinterpret_cast<const uint4*>(
                qw + (size_t)(kr + r) * Q_OUT + nb * 64 + 4 * c16);
    };
    auto LOADA = [&](int c, int set) {
        const uint4* ab = xq + (size_t)(kb * NCH + c) * 128;
        A[set][0] = ab[lane];
        A[set][1] = ab[64 + lane];
    };
    auto WLDS = [&](int buf, int set) {
        const int kd = 4 * wid + qr;
        #pragma unroll
        for (int j = 0; j < 4; ++j) {
            // vertical pack: byte j of rows 0..3 (upper 24 bits are zero)
            uint pw = (((uint*)&d[set][0])[j])        |
                      ((((uint*)&d[set][1])[j]) << 8)  |
                      ((((uint*)&d[set][2])[j]) << 16) |
                      ((((uint*)&d[set][3])[j]) << 24);
            b_lds[buf][(4 * c16 + j) * BST + kd] = (int)pw;
        }
    };

    LOADB(0, 0);
    LOADA(0, 0);
    LOADB(1, 1);
    LOADA(1, 1);
    WLDS(0, 0);
    asm volatile("s_waitcnt lgkmcnt(0)" ::: "memory");
    __builtin_amdgcn_s_barrier();
    asm volatile("" ::: "memory");

    #pragma unroll
    for (int c = 0; c < NCH; ++c) {
        const int cur = c & 1;
        const int gl  = c >> 1;
        if (c + 2 < NCH) LOADB(c + 2, cur);   // d[cur] flushed by WLDS at c-1
        if ((c & 1) == 0) {   // group start: fetch Sx rows (L2-hot)
            sx0v = *reinterpret_cast<const int4*>(Sx + (g0 + gl) * 32 + kg * 4);
            sx1v = *reinterpret_cast<const int4*>(Sx + (g0 + gl) * 32 + 16 + kg * 4);
        }

        #pragma unroll
        for (int nf = 0; nf < 2; ++nf) {
            const int nw = wid * 16 + nf * 8 + (cl >> 1);
            const int* bp = &b_lds[cur][nw * BST + 4 * kg];
            i32x4 bv;
            bv[0] = (int)(((uint)bp[0] >> shn) & 0x0F0F0F0Fu);
            bv[1] = (int)(((uint)bp[1] >> shn) & 0x0F0F0F0Fu);
            bv[2] = (int)(((uint)bp[2] >> shn) & 0x0F0F0F0Fu);
            bv[3] = (int)(((uint)bp[3] >> shn) & 0x0F0F0F0Fu);
            acc_i[0][nf] = __builtin_amdgcn_mfma_i32_16x16x64_i8(
                __builtin_bit_cast(i32x4, A[cur][0]), bv, acc_i[0][nf], 0, 0, 0);
            acc_i[1][nf] = __builtin_amdgcn_mfma_i32_16x16x64_i8(
                __builtin_bit_cast(i32x4, A[cur][1]), bv, acc_i[1][nf], 0, 0, 0);
        }

        // A prefetch AFTER consumption (same register set; r7 lesson)
        if (c + 2 < NCH) LOADA(c + 2, cur);

        if (c & 1) {          // group end: integer zero-point fixup, scale
            int sxa[8] = { sx0v.x, sx0v.y, sx0v.z, sx0v.w,
                           sx1v.x, sx1v.y, sx1v.z, sx1v.w };
            #pragma unroll
            for (int f = 0; f < 2; ++f)
                #pragma unroll
                for (int nf = 0; nf < 2; ++nf)
                    #pragma unroll
                    for (int r = 0; r < 4; ++r) {
                        int tt = acc_i[f][nf][r] - zv[gl][nf] * sxa[f * 4 + r];
                        accf[f][nf][r] = fmaf(sv[gl][nf], (float)tt, accf[f][nf][r]);
                    }
            #pragma unroll
            for (int f = 0; f < 2; ++f)
                #pragma unroll
                for (int nf = 0; nf < 2; ++nf)
                    acc_i[f][nf] = i32x4{0, 0, 0, 0};
        }

        if (c + 1 < NCH) {
            WLDS(cur ^ 1, cur ^ 1);
            asm volatile("s_waitcnt lgkmcnt(0)" ::: "memory");
            __builtin_amdgcn_s_barrier();
            asm volatile("" ::: "memory");
        }
    }

    // epilogue: C/D layout col=lane&15, row=(lane>>4)*4+reg; out += delta_m*accf
    float4 dl0 = *reinterpret_cast<const float4*>(delta + kg * 4);
    float4 dl1 = *reinterpret_cast<const float4*>(delta + 16 + kg * 4);
    const float dla[8] = { dl0.x, dl0.y, dl0.z, dl0.w, dl1.x, dl1.y, dl1.z, dl1.w };
    #pragma unroll
    for (int f = 0; f < 2; ++f)
        #pragma unroll
        for (int nf = 0; nf < 2; ++nf)
            #pragma unroll
            for (int r = 0; r < 4; ++r) {
                const int m = f * 16 + kg * 4 + r;
                unsafeAtomicAdd(out + (size_t)m * OUT_F + n + nf * 16,
                                dla[f * 4 + r] * accf[f][nf][r]);
            }
}

extern "C" void kernel_launch(void* const* d_in, const int* in_sizes, int n_in,
                              void* d_out, int out_size, void* d_ws, size_t ws_size,
                              hipStream_t stream)
{
    const float* inp    = (const float*)d_in[0];
    const int*   qw     = (const int*)d_in[1];
    const float* scales = (const float*)d_in[2];
    const int*   qz     = (const int*)d_in[3];
    const float* bias   = (const float*)d_in[4];
    float*       out    = (float*)d_out;

    uint4* xq    = (uint4*)d_ws;                          // 128 KB
    int*   Sx    = (int*)((char*)d_ws + 131072);          // 4 KB
    float* delta = (float*)((char*)d_ws + 131072 + 4096); // 128 B

    // blocks 0..31: quantize rows + Sx + delta; blocks 32..117: out = bias
    prep_kernel<<<118, 256, 0, stream>>>(inp, bias, xq, Sx, delta, out);

    int4_gemm_i8<<<dim3(OUT_F / BN, KBS), 256, 0, stream>>>(
        xq, qw, scales, qz, Sx, delta, out);
}

// Round 9
// 27.957 us; speedup vs baseline: 1.2588x; 1.2588x over previous
//
#include <hip/hip_runtime.h>
#include <cstdint>

#define IN_F 4096
#define OUT_F 11008
#define Q_OUT 5504
#define GROUP 128
#define BATCH 32

#define KBS 8            // k-splits (gridDim.y)
#define GPB 4            // quant groups per block
#define NCH 8            // 64-k chunks per block (K=512)
#define BN 64            // output cols per block
#define BST 18           // b_lds dword stride per n-row: 16 data + 2 pad
#define DEPTH 4          // B register-prefetch depth (chunks in flight)

typedef int   i32x4 __attribute__((ext_vector_type(4)));
typedef float f32x4 __attribute__((ext_vector_type(4)));

// ---------------------------------------------------------------------------
// Prep kernel, two roles by blockIdx:
//  blocks 0..31: row m: maxabs -> delta[m]; quantize x to i8 in MFMA A-frag
//    order; per-group row sums Sx[g][m] (i32, exact).
//  blocks 32..117: out[m][n] = bias[n]  (16 floats/thread; gemm atomics add)
// ---------------------------------------------------------------------------
__global__ __launch_bounds__(256)
void prep_kernel(const float* __restrict__ x,
                 const float* __restrict__ bias,
                 uint4* __restrict__ xq,     // 8192 slots of 16 i8
                 int*   __restrict__ Sx,     // [32 g][32 m]
                 float* __restrict__ delta,  // [32]
                 float* __restrict__ out)
{
    const int t = threadIdx.x;
    if (blockIdx.x >= 32) {
        const int base = (blockIdx.x - 32) * 4096 + t * 16;
        #pragma unroll
        for (int i = 0; i < 4; ++i)
            *reinterpret_cast<float4*>(out + base + i * 4) =
                *reinterpret_cast<const float4*>(bias + ((base + i * 4) % OUT_F));
        return;
    }
    const int m = blockIdx.x;
    const float* xr = x + (size_t)m * IN_F + t * 16;  // thread owns k=16t..16t+15
    float4 v[4];
    #pragma unroll
    for (int i = 0; i < 4; ++i) v[i] = reinterpret_cast<const float4*>(xr)[i];

    float lm = 0.f;
    #pragma unroll
    for (int i = 0; i < 4; ++i) {
        lm = fmaxf(lm, fmaxf(fmaxf(fabsf(v[i].x), fabsf(v[i].y)),
                             fmaxf(fabsf(v[i].z), fabsf(v[i].w))));
    }
    #pragma unroll
    for (int d = 32; d; d >>= 1) lm = fmaxf(lm, __shfl_xor(lm, d));
    __shared__ float wred[4];
    if ((t & 63) == 0) wred[t >> 6] = lm;
    __syncthreads();
    const float mx  = fmaxf(fmaxf(wred[0], wred[1]), fmaxf(wred[2], wred[3]));
    const float inv = mx > 0.f ? 127.0f / mx : 0.f;

    int q[16];
    #pragma unroll
    for (int i = 0; i < 4; ++i) {
        q[i * 4 + 0] = __float2int_rn(v[i].x * inv);
        q[i * 4 + 1] = __float2int_rn(v[i].y * inv);
        q[i * 4 + 2] = __float2int_rn(v[i].z * inv);
        q[i * 4 + 3] = __float2int_rn(v[i].w * inv);
    }
    uint4 w;
    uint* wp = reinterpret_cast<uint*>(&w);
    #pragma unroll
    for (int i = 0; i < 4; ++i)
        wp[i] = (q[i*4] & 255) | ((q[i*4+1] & 255) << 8) |
                ((q[i*4+2] & 255) << 16) | ((q[i*4+3] & 255) << 24);
    // slot = S*128 + f*64 + kg*16 + (m&15);  S=t>>2, kg=t&3, f=m>>4
    xq[(t >> 2) * 128 + (m >> 4) * 64 + (t & 3) * 16 + (m & 15)] = w;

    int psum = 0;
    #pragma unroll
    for (int i = 0; i < 16; ++i) psum += q[i];
    #pragma unroll
    for (int d = 4; d; d >>= 1) psum += __shfl_down(psum, d, 8);
    if ((t & 7) == 0) Sx[(t >> 3) * 32 + m] = psum;   // g = t>>3
    if (t == 0) delta[m] = mx * (1.0f / 127.0f);
}

// ---------------------------------------------------------------------------
// GEMM: per block M=32, N=64, K=512 (4 groups). 4 waves, each 16 cols.
// == r5 kernel (28.4 us) with ONE change: B prefetch depth 2 -> 4. ==
// A: i8 frags, 16 KB staged once via global_load_lds; 2 x ds_read_b128/chunk.
// B: nibbles unpacked to i8 bytes in LDS [64 n][16+2 dwords]; 4-deep register
//    prefetch (chunk x loaded at iter x-4, ds_written at iter x-1 -> ~3 iters
//    of latency slack vs r5's 1). Raw s_barrier + lgkmcnt(0) only in loop.
// Per group (2 chunks): acc_i32 -> accf += s*(D - z*Sx).
// Epilogue: out += delta_m * accf via unsafeAtomicAdd (out = bias by prep).
// ---------------------------------------------------------------------------
__global__ __launch_bounds__(256, 4)
void int4_gemm_i8(const uint4* __restrict__ xq,
                  const int*   __restrict__ qw,
                  const float* __restrict__ scales,
                  const int*   __restrict__ qz,
                  const int*   __restrict__ Sx,
                  const float* __restrict__ delta,
                  float*       __restrict__ out)
{
    const int tid  = threadIdx.x;
    const int lane = tid & 63;
    const int wid  = tid >> 6;
    const int nb   = blockIdx.x;          // 0..171
    const int kb   = blockIdx.y;          // 0..7
    const int g0   = kb * GPB;
    const int k0b  = g0 * GROUP;

    __shared__ uint4 a_lds[1024];         // 16 KB, read-only after prologue
    __shared__ int   b_lds[2][64 * BST];  // 2 x 4.5 KB

    const int cl  = lane & 15;
    const int kg  = lane >> 4;
    const int n   = nb * BN + wid * 16 + cl;
    const int shn = (cl & 1) * 4;

    // ---- A stage: this kb's 1024 contiguous uint4 slots -> LDS, linear ----
    #pragma unroll
    for (int r = 0; r < 4; ++r) {
        const uint4* gp = xq + (size_t)kb * 1024 + r * 256 + tid;
        __builtin_amdgcn_global_load_lds(
            (const __attribute__((address_space(1))) uint32_t*)gp,
            (__attribute__((address_space(3))) uint32_t*)&a_lds[r * 256 + wid * 64],
            16, 0, 0);
    }

    // per-group constants
    int   zv[GPB];
    float sv[GPB];
    #pragma unroll
    for (int g = 0; g < GPB; ++g) {
        sv[g] = scales[(size_t)(g0 + g) * OUT_F + n];
        zv[g] = (qz[(size_t)(g0 + g) * Q_OUT + (n >> 1)] >> shn) & 15;
    }

    // B staging: thread (a16 = words 2a16,2a16+1; rk = rows 4rk..4rk+3)
    const int a16 = tid & 15;
    const int rk  = tid >> 4;

    uint2 d[DEPTH][4];                    // [set][row]; set s holds chunk c, s = c&3
    i32x4 acc_i[2] = {};
    f32x4 accf[2]  = {};
    int4  sx0v = {}, sx1v = {};

    auto LOADB = [&](int c, int set) {
        const int kr = k0b + c * 64 + 4 * rk;
        #pragma unroll
        for (int i = 0; i < 4; ++i)
            d[set][i] = *reinterpret_cast<const uint2*>(
                qw + (size_t)(kr + i) * Q_OUT + nb * 32 + 2 * a16);
    };
    auto WLDS = [&](int buf, int set) {
        #pragma unroll
        for (int j = 0; j < 2; ++j) {
            // k-major dword: low bytes of 4 consecutive k-rows, word 2a16+j
            uint b0 = (j ? d[set][0].y : d[set][0].x) & 255u;
            uint b1 = (j ? d[set][1].y : d[set][1].x) & 255u;
            uint b2 = (j ? d[set][2].y : d[set][2].x) & 255u;
            uint b3 = (j ? d[set][3].y : d[set][3].x) & 255u;
            uint p  = b0 | (b1 << 8) | (b2 << 16) | (b3 << 24);
            const int nloc = 4 * a16 + 2 * j;
            b_lds[buf][(nloc + 0) * BST + rk] = (int)(p & 0x0F0F0F0Fu);
            b_lds[buf][(nloc + 1) * BST + rk] = (int)((p >> 4) & 0x0F0F0F0Fu);
        }
    };

    LOADB(0, 0);
    LOADB(1, 1);
    LOADB(2, 2);
    LOADB(3, 3);
    WLDS(0, 0);
    asm volatile("s_waitcnt vmcnt(0) lgkmcnt(0)" ::: "memory");
    __builtin_amdgcn_s_barrier();
    asm volatile("" ::: "memory");

    #pragma unroll
    for (int c = 0; c < NCH; ++c) {
        const int cur = c & 1;
        const int gl  = c >> 1;
        // refill: set c&3 was consumed by WLDS at iter c-1 (wrote chunk c);
        // chunk c+4 lives in set (c+4)&3 == c&3. 3 iters of slack to its use.
        if (c + DEPTH < NCH) LOADB(c + DEPTH, c & 3);
        if ((c & 1) == 0) {   // group start: fetch Sx rows (L2-hot)
            sx0v = *reinterpret_cast<const int4*>(Sx + (g0 + gl) * 32 + kg * 4);
            sx1v = *reinterpret_cast<const int4*>(Sx + (g0 + gl) * 32 + 16 + kg * 4);
        }

        // B fragment: n-row (already nibble-extracted i8), dwords 4kg..4kg+3
        const int* bp = &b_lds[cur][(wid * 16 + cl) * BST + 4 * kg];
        int2 qa = *reinterpret_cast<const int2*>(bp);
        int2 qb = *reinterpret_cast<const int2*>(bp + 2);
        i32x4 bv; bv[0] = qa.x; bv[1] = qa.y; bv[2] = qb.x; bv[3] = qb.y;

        uint4 a0 = a_lds[(c * 2 + 0) * 64 + lane];
        uint4 a1 = a_lds[(c * 2 + 1) * 64 + lane];
        acc_i[0] = __builtin_amdgcn_mfma_i32_16x16x64_i8(
            __builtin_bit_cast(i32x4, a0), bv, acc_i[0], 0, 0, 0);
        acc_i[1] = __builtin_amdgcn_mfma_i32_16x16x64_i8(
            __builtin_bit_cast(i32x4, a1), bv, acc_i[1], 0, 0, 0);

        if (c & 1) {          // group end: integer zero-point fixup, scale
            const int   zz = zv[gl];
            const float ss = sv[gl];
            int sxa[8] = { sx0v.x, sx0v.y, sx0v.z, sx0v.w,
                           sx1v.x, sx1v.y, sx1v.z, sx1v.w };
            #pragma unroll
            for (int f = 0; f < 2; ++f)
                #pragma unroll
                for (int r = 0; r < 4; ++r) {
                    int tt = acc_i[f][r] - zz * sxa[f * 4 + r];
                    accf[f][r] = fmaf(ss, (float)tt, accf[f][r]);
                }
            acc_i[0] = i32x4{0, 0, 0, 0};
            acc_i[1] = i32x4{0, 0, 0, 0};
        }

        if (c + 1 < NCH) {
            // chunk c+1 -> LDS from set (c+1)&3 (loaded at iter c-3)
            WLDS(cur ^ 1, (c + 1) & 3);
            asm volatile("s_waitcnt lgkmcnt(0)" ::: "memory");
            __builtin_amdgcn_s_barrier();
            asm volatile("" ::: "memory");
        }
    }

    // epilogue: C/D layout col=lane&15, row=(lane>>4)*4+reg; out += delta_m*accf
    float4 dl0 = *reinterpret_cast<const float4*>(delta + kg * 4);
    float4 dl1 = *reinterpret_cast<const float4*>(delta + 16 + kg * 4);
    const float dla[8] = { dl0.x, dl0.y, dl0.z, dl0.w, dl1.x, dl1.y, dl1.z, dl1.w };
    #pragma unroll
    for (int f = 0; f < 2; ++f)
        #pragma unroll
        for (int r = 0; r < 4; ++r) {
            const int m = f * 16 + kg * 4 + r;
            unsafeAtomicAdd(out + (size_t)m * OUT_F + n, dla[f * 4 + r] * accf[f][r]);
        }
}

extern "C" void kernel_launch(void* const* d_in, const int* in_sizes, int n_in,
                              void* d_out, int out_size, void* d_ws, size_t ws_size,
                              hipStream_t stream)
{
    const float* inp    = (const float*)d_in[0];
    const int*   qw     = (const int*)d_in[1];
    const float* scales = (const float*)d_in[2];
    const int*   qz     = (const int*)d_in[3];
    const float* bias   = (const float*)d_in[4];
    float*       out    = (float*)d_out;

    uint4* xq    = (uint4*)d_ws;                          // 128 KB
    int*   Sx    = (int*)((char*)d_ws + 131072);          // 4 KB
    float* delta = (float*)((char*)d_ws + 131072 + 4096); // 128 B

    // blocks 0..31: quantize rows + Sx + delta; blocks 32..117: out = bias
    prep_kernel<<<118, 256, 0, stream>>>(inp, bias, xq, Sx, delta, out);

    int4_gemm_i8<<<dim3(OUT_F / BN, KBS), 256, 0, stream>>>(
        xq, qw, scales, qz, Sx, delta, out);
}